// Round 5
// baseline (222.800 us; speedup 1.0000x reference)
//
#include <hip/hip_runtime.h>

// Sliding-window attention (W=512 causal window, first 64 queries global, non-causal)
// B=2 H=16 S=4096 D=64, fp32 in/out, bf16 MFMA compute.
//
// Structure:
//  - banded path: 1 block per (bh, 64-query tile 1..63); 4 waves x 16 queries;
//    iterate <=9 KV blocks of 64 keys; shared LDS staging (fragment-order, lane-linear).
//  - global path: 4 blocks per bh, each 16 queries; 4 waves split the 4096 keys
//    (wave-private 8KB LDS regions, no barriers in loop); in-block LSE merge.
//  - QK^T swapped (mfma(K,Q)) so softmax is per-lane + 2 shfl_xor.
//  - PV uses the SAME 16x16x32 mfma: two 16-key P tiles fused into one K=32
//    B-fragment (k map = 4g + (j&3) + 16*(j>>2), matching the QK C-layout rows);
//    V^T fragments staged with the identical map -> no P transpose, no K=16 mfma.

typedef __attribute__((ext_vector_type(4))) float  f32x4;
typedef __attribute__((ext_vector_type(8))) short  s16x8;

#define S_LEN  4096
#define D_HEAD 64
#define SCALE_L2 (0.125f * 1.44269504088896340736f)  /* 1/sqrt(64) * log2(e) */
#define MINIT  (-1e5f)
#define MASKV  (-1e30f)

static __device__ __forceinline__ short f2bf(float x) {
  unsigned u = __builtin_bit_cast(unsigned, x);
  return (short)((u + 0x8000u) >> 16);   // round-half-up to bf16
}

static __device__ __forceinline__ f32x4 mfma32(s16x8 a, s16x8 b, f32x4 c) {
  return __builtin_amdgcn_mfma_f32_16x16x32_bf16(a, b, c, 0, 0, 0);
}

extern "C" __global__ void __launch_bounds__(256, 4)
swa_fused_kernel(const float* __restrict__ qg, const float* __restrict__ kg,
                 const float* __restrict__ vg, float* __restrict__ outg) {
  __shared__ __align__(16) char LDSBUF[32768];
  __shared__ float MLB[4][2][16];

  const int tid = threadIdx.x;
  const int w   = tid >> 6;   // wave id 0..3
  const int l   = tid & 63;   // lane
  const int g   = l >> 4;     // 16-lane group 0..3
  const int ql  = l & 15;
  const int bi  = blockIdx.x;

  if (bi < 128) {
    // ---------------- global-prefix path ----------------
    const int bh = bi >> 2, qsub = bi & 3;
    const float* Q = qg + (size_t)bh * S_LEN * D_HEAD;
    const float* K = kg + (size_t)bh * S_LEN * D_HEAD;
    const float* V = vg + (size_t)bh * S_LEN * D_HEAD;
    float* O = outg + (size_t)bh * S_LEN * D_HEAD;
    const int qrow = qsub * 16 + ql;

    s16x8 qf[2];
#pragma unroll
    for (int h = 0; h < 2; ++h) {
      const float* p = Q + qrow * 64 + h * 32 + g * 8;
      f32x4 a = *(const f32x4*)p, b = *(const f32x4*)(p + 4);
      s16x8 r;
#pragma unroll
      for (int e = 0; e < 4; ++e) { r[e] = f2bf(a[e] * SCALE_L2); r[4 + e] = f2bf(b[e] * SCALE_L2); }
      qf[h] = r;
    }

    short* kfw = (short*)(LDSBUF + w * 8192);
    short* vfw = (short*)(LDSBUF + w * 8192 + 4096);

    f32x4 acc[4] = {{0,0,0,0},{0,0,0,0},{0,0,0,0},{0,0,0,0}};
    float m = MINIT, lsum = 0.f;

    for (int it = 0; it < 32; ++it) {
      const int k0 = w * 1024 + it * 32;
      // stage K (wave-private, fragment order): 4 frags cover 32 keys x 64 d
#pragma unroll
      for (int fb = 0; fb < 4; ++fb) {
        int row = k0 + ((fb >> 1) << 4) + ql;
        int d0  = ((fb & 1) << 5) + (g << 3);
        const float* p = K + row * 64 + d0;
        f32x4 a = *(const f32x4*)p, b = *(const f32x4*)(p + 4);
        s16x8 r;
#pragma unroll
        for (int e = 0; e < 4; ++e) { r[e] = f2bf(a[e]); r[4 + e] = f2bf(b[e]); }
        *(s16x8*)(kfw + (fb * 64 + l) * 8) = r;
      }
      // stage V^T fragments (K=32 map: k = 4g + (j&3) + 16*(j>>2)): 4 frags (dt)
#pragma unroll
      for (int fb = 0; fb < 4; ++fb) {
        int dd = fb * 16 + ql;
        int kk = k0 + (g << 2);
        const float* p = V + kk * 64 + dd;
        s16x8 r;
#pragma unroll
        for (int j = 0; j < 4; ++j) { r[j] = f2bf(p[j * 64]); r[4 + j] = f2bf(p[(16 + j) * 64]); }
        *(s16x8*)(vfw + (fb * 64 + l) * 8) = r;
      }
      // QK^T (swapped): 2 key subtiles of 16
      f32x4 c[2];
#pragma unroll
      for (int kt = 0; kt < 2; ++kt) {
        s16x8 a0 = *(const s16x8*)(kfw + ((kt * 2 + 0) * 64 + l) * 8);
        s16x8 a1 = *(const s16x8*)(kfw + ((kt * 2 + 1) * 64 + l) * 8);
        f32x4 cc = {0,0,0,0};
        cc = mfma32(a0, qf[0], cc);
        cc = mfma32(a1, qf[1], cc);
        c[kt] = cc;
      }
      // online softmax (per-lane query, keys across g-groups)
      float rm = MASKV;
#pragma unroll
      for (int kt = 0; kt < 2; ++kt)
#pragma unroll
        for (int r = 0; r < 4; ++r) rm = fmaxf(rm, c[kt][r]);
      rm = fmaxf(rm, __shfl_xor(rm, 16));
      rm = fmaxf(rm, __shfl_xor(rm, 32));
      float mn = fmaxf(m, rm);
      float al = __builtin_amdgcn_exp2f(m - mn);
      float rs = 0.f;
      float pv[2][4];
#pragma unroll
      for (int kt = 0; kt < 2; ++kt)
#pragma unroll
        for (int r = 0; r < 4; ++r) { float e2 = __builtin_amdgcn_exp2f(c[kt][r] - mn); pv[kt][r] = e2; rs += e2; }
      rs += __shfl_xor(rs, 16);
      rs += __shfl_xor(rs, 32);
      lsum = lsum * al + rs;
      m = mn;
#pragma unroll
      for (int dt = 0; dt < 4; ++dt) acc[dt] *= al;
      // fuse the two 16-key P tiles into one K=32 B fragment
      s16x8 pb;
#pragma unroll
      for (int r = 0; r < 4; ++r) { pb[r] = f2bf(pv[0][r]); pb[4 + r] = f2bf(pv[1][r]); }
#pragma unroll
      for (int dt = 0; dt < 4; ++dt) {
        s16x8 vf = *(const s16x8*)(vfw + (dt * 64 + l) * 8);
        acc[dt] = mfma32(vf, pb, acc[dt]);
      }
    }
    // merge the 4 waves' partial softmaxes (same 16 queries, disjoint keys)
    if (g == 0) { MLB[w][0][ql] = m; MLB[w][1][ql] = lsum; }
    __syncthreads();
    {
      float M = fmaxf(fmaxf(MLB[0][0][ql], MLB[1][0][ql]), fmaxf(MLB[2][0][ql], MLB[3][0][ql]));
      float f = __builtin_amdgcn_exp2f(m - M);
      float* mrg = (float*)LDSBUF;  // safe after barrier: loop done reading kfw/vfw
#pragma unroll
      for (int dt = 0; dt < 4; ++dt) {
        f32x4 o = acc[dt] * f;
        *(f32x4*)(mrg + ((w * 4 + dt) * 64 + l) * 4) = o;
      }
    }
    __syncthreads();
    {
      float* mrg = (float*)LDSBUF;
      const int dt = tid >> 6, ln = tid & 63;
      f32x4 s = {0,0,0,0};
#pragma unroll
      for (int ww = 0; ww < 4; ++ww) s += *(const f32x4*)(mrg + ((ww * 4 + dt) * 64 + ln) * 4);
      const int qq = ln & 15;
      float M2 = fmaxf(fmaxf(MLB[0][0][qq], MLB[1][0][qq]), fmaxf(MLB[2][0][qq], MLB[3][0][qq]));
      float L2 = MLB[0][1][qq] * __builtin_amdgcn_exp2f(MLB[0][0][qq] - M2)
               + MLB[1][1][qq] * __builtin_amdgcn_exp2f(MLB[1][0][qq] - M2)
               + MLB[2][1][qq] * __builtin_amdgcn_exp2f(MLB[2][0][qq] - M2)
               + MLB[3][1][qq] * __builtin_amdgcn_exp2f(MLB[3][0][qq] - M2);
      s *= (1.0f / L2);
      *(f32x4*)(O + (size_t)(qsub * 16 + qq) * 64 + dt * 16 + (ln >> 4) * 4) = s;
    }
    return;
  }

  // ---------------- banded (sliding-window) path ----------------
  const int idx  = bi - 128;
  const int bh   = idx / 63;
  const int tile = 1 + (idx % 63);
  const float* Q = qg + (size_t)bh * S_LEN * D_HEAD;
  const float* K = kg + (size_t)bh * S_LEN * D_HEAD;
  const float* V = vg + (size_t)bh * S_LEN * D_HEAD;
  float* O = outg + (size_t)bh * S_LEN * D_HEAD;
  const int qrow = tile * 64 + w * 16 + ql;

  s16x8 qf[2];
#pragma unroll
  for (int h = 0; h < 2; ++h) {
    const float* p = Q + qrow * 64 + h * 32 + g * 8;
    f32x4 a = *(const f32x4*)p, b = *(const f32x4*)(p + 4);
    s16x8 r;
#pragma unroll
    for (int e = 0; e < 4; ++e) { r[e] = f2bf(a[e] * SCALE_L2); r[4 + e] = f2bf(b[e] * SCALE_L2); }
    qf[h] = r;
  }

  short* kfrag = (short*)LDSBUF;
  short* vfrag = (short*)(LDSBUF + 16384);

  f32x4 acc[4] = {{0,0,0,0},{0,0,0,0},{0,0,0,0},{0,0,0,0}};
  float m = MINIT, lsum = 0.f;
  const int kb0 = (tile >= 8) ? (tile - 8) : 0;

  for (int kb = kb0; kb <= tile; ++kb) {
    const int k0 = kb * 64;
    __syncthreads();
    // cooperative stage K fragments (512 slots of 16B): 8 frags cover 64 keys x 64 d
#pragma unroll
    for (int s2 = 0; s2 < 2; ++s2) {
      int s = tid + s2 * 256;
      int fb = s >> 6, ln = s & 63;
      int row = k0 + ((fb >> 1) << 4) + (ln & 15);
      int d0  = ((fb & 1) << 5) + ((ln >> 4) << 3);
      const float* p = K + row * 64 + d0;
      f32x4 a = *(const f32x4*)p, b = *(const f32x4*)(p + 4);
      s16x8 r;
#pragma unroll
      for (int e = 0; e < 4; ++e) { r[e] = f2bf(a[e]); r[4 + e] = f2bf(b[e]); }
      *(s16x8*)(kfrag + s * 8) = r;
    }
    // cooperative stage V^T fragments (512 slots of 16B):
    // frag fb = t*4+dt (t = 32-key half, dt = 16-d tile); k map = 4g + (j&3) + 16*(j>>2)
#pragma unroll
    for (int s2 = 0; s2 < 2; ++s2) {
      int s = tid + s2 * 256;
      int fb = s >> 6, ln = s & 63;
      int t = fb >> 2, dt = fb & 3;
      int dd = dt * 16 + (ln & 15);
      int kk = k0 + t * 32 + ((ln >> 4) << 2);
      const float* p = V + kk * 64 + dd;
      s16x8 r;
#pragma unroll
      for (int j = 0; j < 4; ++j) { r[j] = f2bf(p[j * 64]); r[4 + j] = f2bf(p[(16 + j) * 64]); }
      *(s16x8*)(vfrag + s * 8) = r;
    }
    __syncthreads();

    // QK^T (swapped): 4 key subtiles
    f32x4 c[4];
#pragma unroll
    for (int kt = 0; kt < 4; ++kt) {
      s16x8 a0 = *(const s16x8*)(kfrag + ((kt * 2 + 0) * 64 + l) * 8);
      s16x8 a1 = *(const s16x8*)(kfrag + ((kt * 2 + 1) * 64 + l) * 8);
      f32x4 cc = {0,0,0,0};
      cc = mfma32(a0, qf[0], cc);
      cc = mfma32(a1, qf[1], cc);
      c[kt] = cc;
    }
    // banded mask only on the two boundary KV blocks
    if (kb == tile || kb == tile - 8) {
#pragma unroll
      for (int kt = 0; kt < 4; ++kt)
#pragma unroll
        for (int r = 0; r < 4; ++r) {
          int j = k0 + kt * 16 + g * 4 + r;
          bool ok = (j <= qrow) && (j >= qrow - 511);
          c[kt][r] = ok ? c[kt][r] : MASKV;
        }
    }
    // online softmax
    float rm = MASKV;
#pragma unroll
    for (int kt = 0; kt < 4; ++kt)
#pragma unroll
      for (int r = 0; r < 4; ++r) rm = fmaxf(rm, c[kt][r]);
    rm = fmaxf(rm, __shfl_xor(rm, 16));
    rm = fmaxf(rm, __shfl_xor(rm, 32));
    float mn = fmaxf(m, rm);
    float al = __builtin_amdgcn_exp2f(m - mn);
    float rs = 0.f;
    float pv[4][4];
#pragma unroll
    for (int kt = 0; kt < 4; ++kt)
#pragma unroll
      for (int r = 0; r < 4; ++r) { float e2 = __builtin_amdgcn_exp2f(c[kt][r] - mn); pv[kt][r] = e2; rs += e2; }
    rs += __shfl_xor(rs, 16);
    rs += __shfl_xor(rs, 32);
    lsum = lsum * al + rs;
    m = mn;
#pragma unroll
    for (int dt = 0; dt < 4; ++dt) acc[dt] *= al;
    // PV: two K=32 blocks, each fusing two 16-key P tiles into one B fragment
#pragma unroll
    for (int t = 0; t < 2; ++t) {
      s16x8 pb;
#pragma unroll
      for (int r = 0; r < 4; ++r) { pb[r] = f2bf(pv[2 * t][r]); pb[4 + r] = f2bf(pv[2 * t + 1][r]); }
#pragma unroll
      for (int dt = 0; dt < 4; ++dt) {
        s16x8 vf = *(const s16x8*)(vfrag + ((t * 4 + dt) * 64 + l) * 8);
        acc[dt] = mfma32(vf, pb, acc[dt]);
      }
    }
  }

  // epilogue: consecutive d lives in the reg dim -> 16B stores per lane
  const float inv = 1.0f / lsum;
#pragma unroll
  for (int dt = 0; dt < 4; ++dt) {
    f32x4 o = acc[dt] * inv;
    *(f32x4*)(O + (size_t)qrow * 64 + dt * 16 + g * 4) = o;
  }
}

extern "C" void kernel_launch(void* const* d_in, const int* in_sizes, int n_in,
                              void* d_out, int out_size, void* d_ws, size_t ws_size,
                              hipStream_t stream) {
  (void)in_sizes; (void)n_in; (void)d_ws; (void)ws_size; (void)out_size;
  const float* q = (const float*)d_in[0];
  const float* k = (const float*)d_in[1];
  const float* v = (const float*)d_in[2];
  float* o = (float*)d_out;
  // 128 global-prefix blocks first (long-ish), then 32*63 banded blocks
  dim3 grid(128 + 32 * 63), block(256);
  hipLaunchKernelGGL(swa_fused_kernel, grid, block, 0, stream, q, k, v, o);
}

// Round 6
// 193.414 us; speedup vs baseline: 1.1519x; 1.1519x over previous
//
#include <hip/hip_runtime.h>

// Sliding-window attention (W=512 causal, first 64 queries global/non-causal)
// B=2 H=16 S=4096 D=64, fp32 in/out, bf16 MFMA compute.
//
// Round-5 restructure (fetch-bound per rocprof: 413MB fetch vs 100MB unique):
//  - banded: QT=256 queries/block (4 waves x 4 q-tiles of 16) -> KV re-fetch 9x -> 3x
//  - global: 1 block/bh, 4 waves x 16 q, sweep all keys (no merge) -> KV 4x -> 1x
//  - XCD co-location: blockIdx = t*32 + bh => XCD = bh%8; all blocks of a bh share L2
//  - double-buffered KV staging, single barrier/iter; loads issued before compute (T14)
//  - verified maps kept: swapped QK^T; PV fused K=32 (k map = 4g+(e&3)+16*(e>>2))

typedef __attribute__((ext_vector_type(4))) float  f32x4;
typedef __attribute__((ext_vector_type(8))) short  s16x8;

#define S_LEN  4096
#define D_HEAD 64
#define SCALE_L2 (0.125f * 1.44269504088896340736f)  /* 1/sqrt(64) * log2(e) */
#define MINIT  (-1e5f)
#define MASKV  (-1e30f)

static __device__ __forceinline__ short f2bf(float x) {
  unsigned u = __builtin_bit_cast(unsigned, x);
  return (short)((u + 0x8000u) >> 16);   // round-half-up to bf16
}

static __device__ __forceinline__ f32x4 mfma32(s16x8 a, s16x8 b, f32x4 c) {
  return __builtin_amdgcn_mfma_f32_16x16x32_bf16(a, b, c, 0, 0, 0);
}

// Cooperative staging of one 64-key KV block (256 threads, 512 slots of 16B each
// for K and V). Split into load (global->regs, issued early) and write
// (cvt + regs->LDS, after compute) so HBM latency hides under the MFMA phase.
struct Stage {
  f32x4 ka[2][2];
  float vs[2][8];
};

static __device__ __forceinline__ void stage_load(const float* __restrict__ K,
                                                  const float* __restrict__ V,
                                                  int k0, int tid, Stage& st) {
#pragma unroll
  for (int i = 0; i < 2; ++i) {
    int s = tid + i * 256;
    int fb = s >> 6, ln = s & 63;
    {
      // K fragment slot: row = k0 + kt*16 + ql, d = half*32 + g*8 .. +7
      int row = k0 + ((fb >> 1) << 4) + (ln & 15);
      int d0  = ((fb & 1) << 5) + ((ln >> 4) << 3);
      const float* p = K + row * 64 + d0;
      st.ka[i][0] = *(const f32x4*)p;
      st.ka[i][1] = *(const f32x4*)(p + 4);
    }
    {
      // V^T fragment slot (K=32 fused map: k = 4g + (j&3) + 16*(j>>2))
      int t = fb >> 2, dt = fb & 3;
      int dd = dt * 16 + (ln & 15);
      int kk = k0 + t * 32 + ((ln >> 4) << 2);
      const float* p = V + kk * 64 + dd;
#pragma unroll
      for (int j = 0; j < 4; ++j) { st.vs[i][j] = p[j * 64]; st.vs[i][4 + j] = p[(16 + j) * 64]; }
    }
  }
}

static __device__ __forceinline__ void stage_write(short* kf, short* vf, int tid, const Stage& st) {
#pragma unroll
  for (int i = 0; i < 2; ++i) {
    int s = tid + i * 256;
    s16x8 kr, vr;
#pragma unroll
    for (int e = 0; e < 4; ++e) { kr[e] = f2bf(st.ka[i][0][e]); kr[4 + e] = f2bf(st.ka[i][1][e]); }
#pragma unroll
    for (int e = 0; e < 8; ++e) vr[e] = f2bf(st.vs[i][e]);
    *(s16x8*)(kf + s * 8) = kr;
    *(s16x8*)(vf + s * 8) = vr;
  }
}

extern "C" __global__ void __launch_bounds__(256, 2)
swa_fused_kernel(const float* __restrict__ qg, const float* __restrict__ kg,
                 const float* __restrict__ vg, float* __restrict__ outg) {
  __shared__ __align__(16) short KB[2][4096];   // 2 x 8KB bf16 K fragments
  __shared__ __align__(16) short VB[2][4096];   // 2 x 8KB bf16 V^T fragments

  const int tid = threadIdx.x;
  const int w  = tid >> 6;    // wave 0..3
  const int l  = tid & 63;
  const int g  = l >> 4;
  const int ql = l & 15;
  const int bx = blockIdx.x;
  const int t  = bx >> 5;     // 0 = global path, 1..16 = banded tile t-1
  const int bh = bx & 31;     // bh%8 == bx%8 -> same-bh blocks share an XCD L2

  const float* Q = qg + (size_t)bh * S_LEN * D_HEAD;
  const float* K = kg + (size_t)bh * S_LEN * D_HEAD;
  const float* V = vg + (size_t)bh * S_LEN * D_HEAD;
  float* O = outg + (size_t)bh * S_LEN * D_HEAD;

  Stage st;

  if (t == 0) {
    // ---------------- global-prefix path: rows 0..63 over all 4096 keys ----------------
    const int qrow = w * 16 + ql;
    s16x8 qf[2];
#pragma unroll
    for (int h = 0; h < 2; ++h) {
      const float* p = Q + qrow * 64 + h * 32 + g * 8;
      f32x4 a = *(const f32x4*)p, b = *(const f32x4*)(p + 4);
      s16x8 r;
#pragma unroll
      for (int e = 0; e < 4; ++e) { r[e] = f2bf(a[e] * SCALE_L2); r[4 + e] = f2bf(b[e] * SCALE_L2); }
      qf[h] = r;
    }
    f32x4 acc[4] = {{0,0,0,0},{0,0,0,0},{0,0,0,0},{0,0,0,0}};
    float m = MINIT, lsum = 0.f;

    stage_load(K, V, 0, tid, st);
    stage_write(KB[0], VB[0], tid, st);
    __syncthreads();
    int cur = 0;
    for (int kb = 0; kb < 64; ++kb) {
      if (kb < 63) stage_load(K, V, (kb + 1) * 64, tid, st);
      const short* kf = KB[cur];
      const short* vf = VB[cur];
      f32x4 c[4];
#pragma unroll
      for (int kt = 0; kt < 4; ++kt) {
        s16x8 a0 = *(const s16x8*)(kf + ((kt * 2 + 0) * 64 + l) * 8);
        s16x8 a1 = *(const s16x8*)(kf + ((kt * 2 + 1) * 64 + l) * 8);
        f32x4 z = {0,0,0,0};
        z = mfma32(a0, qf[0], z);
        c[kt] = mfma32(a1, qf[1], z);
      }
      float rm = MASKV;
#pragma unroll
      for (int kt = 0; kt < 4; ++kt)
#pragma unroll
        for (int r = 0; r < 4; ++r) rm = fmaxf(rm, c[kt][r]);
      rm = fmaxf(rm, __shfl_xor(rm, 16));
      rm = fmaxf(rm, __shfl_xor(rm, 32));
      float mn = fmaxf(m, rm);
      float al = __builtin_amdgcn_exp2f(m - mn);
      float pv[4][4];
      float rs = 0.f;
#pragma unroll
      for (int kt = 0; kt < 4; ++kt)
#pragma unroll
        for (int r = 0; r < 4; ++r) { float e2 = __builtin_amdgcn_exp2f(c[kt][r] - mn); pv[kt][r] = e2; rs += e2; }
      rs += __shfl_xor(rs, 16);
      rs += __shfl_xor(rs, 32);
      lsum = lsum * al + rs;
      m = mn;
#pragma unroll
      for (int dt = 0; dt < 4; ++dt) acc[dt] *= al;
#pragma unroll
      for (int tt = 0; tt < 2; ++tt) {
        s16x8 pb;
#pragma unroll
        for (int r = 0; r < 4; ++r) { pb[r] = f2bf(pv[2 * tt][r]); pb[4 + r] = f2bf(pv[2 * tt + 1][r]); }
#pragma unroll
        for (int dt = 0; dt < 4; ++dt) {
          s16x8 vfr = *(const s16x8*)(vf + ((tt * 4 + dt) * 64 + l) * 8);
          acc[dt] = mfma32(vfr, pb, acc[dt]);
        }
      }
      if (kb < 63) stage_write(KB[cur ^ 1], VB[cur ^ 1], tid, st);
      __syncthreads();
      cur ^= 1;
    }
    const float inv = 1.0f / lsum;
#pragma unroll
    for (int dt = 0; dt < 4; ++dt) {
      f32x4 o = acc[dt] * inv;
      *(f32x4*)(O + (size_t)qrow * 64 + dt * 16 + g * 4) = o;
    }
    return;
  }

  // ---------------- banded path: 256 queries/block, 4 q-tiles per wave ----------------
  const int tb = t - 1;                 // 0..15
  const int Q0 = tb * 256;
  const int qbase = Q0 + w * 64;        // wave's first query row

  s16x8 qf[4][2];
#pragma unroll
  for (int qt = 0; qt < 4; ++qt)
#pragma unroll
    for (int h = 0; h < 2; ++h) {
      const float* p = Q + (qbase + qt * 16 + ql) * 64 + h * 32 + g * 8;
      f32x4 a = *(const f32x4*)p, b = *(const f32x4*)(p + 4);
      s16x8 r;
#pragma unroll
      for (int e = 0; e < 4; ++e) { r[e] = f2bf(a[e] * SCALE_L2); r[4 + e] = f2bf(b[e] * SCALE_L2); }
      qf[qt][h] = r;
    }

  f32x4 acc[4][4];
#pragma unroll
  for (int qt = 0; qt < 4; ++qt)
#pragma unroll
    for (int dt = 0; dt < 4; ++dt) acc[qt][dt] = f32x4{0,0,0,0};
  float mm[4] = {MINIT, MINIT, MINIT, MINIT};
  float ll[4] = {0.f, 0.f, 0.f, 0.f};

  const int kbs = (tb >= 2) ? (4 * tb - 8) : 0;
  const int kbe = 4 * tb + 3;

  stage_load(K, V, kbs * 64, tid, st);
  stage_write(KB[0], VB[0], tid, st);
  __syncthreads();
  int cur = 0;
  for (int kb = kbs; kb <= kbe; ++kb) {
    if (kb < kbe) stage_load(K, V, (kb + 1) * 64, tid, st);
    const short* kf = KB[cur];
    const short* vf = VB[cur];

    // QK^T for all 4 q-tiles (K fragments read once, reused across q-tiles)
    f32x4 c[4][4];
#pragma unroll
    for (int kt = 0; kt < 4; ++kt) {
      s16x8 a0 = *(const s16x8*)(kf + ((kt * 2 + 0) * 64 + l) * 8);
      s16x8 a1 = *(const s16x8*)(kf + ((kt * 2 + 1) * 64 + l) * 8);
#pragma unroll
      for (int qt = 0; qt < 4; ++qt) {
        f32x4 z = {0,0,0,0};
        z = mfma32(a0, qf[qt][0], z);
        c[qt][kt] = mfma32(a1, qf[qt][1], z);
      }
    }

    // mask only needed on boundary blocks: interior is kb in [4tb-4, 4tb-1]
    const bool needmask = (kb < 4 * tb - 4) || (kb > 4 * tb - 1);

    s16x8 pbq[4][2];
#pragma unroll
    for (int qt = 0; qt < 4; ++qt) {
      const int qrow = qbase + qt * 16 + ql;
      if (needmask) {
#pragma unroll
        for (int kt = 0; kt < 4; ++kt)
#pragma unroll
          for (int r = 0; r < 4; ++r) {
            int j = kb * 64 + kt * 16 + g * 4 + r;
            bool ok = (j <= qrow) && (j >= qrow - 511);
            c[qt][kt][r] = ok ? c[qt][kt][r] : MASKV;
          }
      }
      float rm = MASKV;
#pragma unroll
      for (int kt = 0; kt < 4; ++kt)
#pragma unroll
        for (int r = 0; r < 4; ++r) rm = fmaxf(rm, c[qt][kt][r]);
      rm = fmaxf(rm, __shfl_xor(rm, 16));
      rm = fmaxf(rm, __shfl_xor(rm, 32));
      float mn = fmaxf(mm[qt], rm);
      float al = __builtin_amdgcn_exp2f(mm[qt] - mn);
      float pv[4][4];
      float rs = 0.f;
#pragma unroll
      for (int kt = 0; kt < 4; ++kt)
#pragma unroll
        for (int r = 0; r < 4; ++r) { float e2 = __builtin_amdgcn_exp2f(c[qt][kt][r] - mn); pv[kt][r] = e2; rs += e2; }
      rs += __shfl_xor(rs, 16);
      rs += __shfl_xor(rs, 32);
      ll[qt] = ll[qt] * al + rs;
      mm[qt] = mn;
#pragma unroll
      for (int dt = 0; dt < 4; ++dt) acc[qt][dt] *= al;
#pragma unroll
      for (int tt = 0; tt < 2; ++tt) {
        s16x8 pb;
#pragma unroll
        for (int r = 0; r < 4; ++r) { pb[r] = f2bf(pv[2 * tt][r]); pb[4 + r] = f2bf(pv[2 * tt + 1][r]); }
        pbq[qt][tt] = pb;
      }
    }

    // PV: V^T fragments read once, reused across all 4 q-tiles
#pragma unroll
    for (int tt = 0; tt < 2; ++tt)
#pragma unroll
      for (int dt = 0; dt < 4; ++dt) {
        s16x8 vfr = *(const s16x8*)(vf + ((tt * 4 + dt) * 64 + l) * 8);
#pragma unroll
        for (int qt = 0; qt < 4; ++qt)
          acc[qt][dt] = mfma32(vfr, pbq[qt][tt], acc[qt][dt]);
      }

    if (kb < kbe) stage_write(KB[cur ^ 1], VB[cur ^ 1], tid, st);
    __syncthreads();
    cur ^= 1;
  }

  // epilogue: skip rows 0..63 (written by the global path)
#pragma unroll
  for (int qt = 0; qt < 4; ++qt) {
    if (qbase + qt * 16 >= 64) {
      const int qrow = qbase + qt * 16 + ql;
      const float inv = 1.0f / ll[qt];
#pragma unroll
      for (int dt = 0; dt < 4; ++dt) {
        f32x4 o = acc[qt][dt] * inv;
        *(f32x4*)(O + (size_t)qrow * 64 + dt * 16 + g * 4) = o;
      }
    }
  }
}

extern "C" void kernel_launch(void* const* d_in, const int* in_sizes, int n_in,
                              void* d_out, int out_size, void* d_ws, size_t ws_size,
                              hipStream_t stream) {
  (void)in_sizes; (void)n_in; (void)d_ws; (void)ws_size; (void)out_size;
  const float* q = (const float*)d_in[0];
  const float* k = (const float*)d_in[1];
  const float* v = (const float*)d_in[2];
  float* o = (float*)d_out;
  // 17 block-rows of 32 bh: row 0 = global-prefix blocks (longest, launched first),
  // rows 1..16 = banded 256-query tiles. blockIdx%8 == bh%8 -> XCD co-location.
  dim3 grid(17 * 32), block(256);
  hipLaunchKernelGGL(swa_fused_kernel, grid, block, 0, stream, q, k, v, o);
}

// Round 7
// 180.538 us; speedup vs baseline: 1.2341x; 1.0713x over previous
//
#include <hip/hip_runtime.h>

// Sliding-window attention (W=512 causal, first 64 queries global/non-causal)
// B=2 H=16 S=4096 D=64, fp32 in/out, bf16 MFMA compute.
//
// Round-6 restructure (latency/imbalance-bound per rocprof: occ 15%, BW 18%):
//  - global path split flash-decoding style: 8 chunk-blocks/bh x 512 keys,
//    partials (acc,m,l) to d_ws; tiny merge kernel for rows 0..63.
//  - banded: unchanged (QT=256, 4 waves x 4 q-tiles, fetch factor 3x).
//  - all blocks now do 4..12 KV iterations -> balanced critical path.
//  - XCD co-location: blockIdx%32 = bh -> bh%8 = XCD; KV of a bh stays in one L2.

typedef __attribute__((ext_vector_type(4))) float  f32x4;
typedef __attribute__((ext_vector_type(8))) short  s16x8;

#define S_LEN  4096
#define D_HEAD 64
#define SCALE_L2 (0.125f * 1.44269504088896340736f)  /* 1/sqrt(64) * log2(e) */
#define MINIT  (-1e5f)
#define MASKV  (-1e30f)
#define NCHUNK 8
#define ACC_WS_FLOATS ((size_t)32 * NCHUNK * 64 * 64)

static __device__ __forceinline__ short f2bf(float x) {
  unsigned u = __builtin_bit_cast(unsigned, x);
  return (short)((u + 0x8000u) >> 16);   // round-half-up to bf16
}

static __device__ __forceinline__ f32x4 mfma32(s16x8 a, s16x8 b, f32x4 c) {
  return __builtin_amdgcn_mfma_f32_16x16x32_bf16(a, b, c, 0, 0, 0);
}

// Cooperative staging of one 64-key KV block (256 threads, 512 slots of 16B each
// for K and V). load (global->regs) issued before compute; write (cvt+LDS) after.
struct Stage {
  f32x4 ka[2][2];
  float vs[2][8];
};

static __device__ __forceinline__ void stage_load(const float* __restrict__ K,
                                                  const float* __restrict__ V,
                                                  int k0, int tid, Stage& st) {
#pragma unroll
  for (int i = 0; i < 2; ++i) {
    int s = tid + i * 256;
    int fb = s >> 6, ln = s & 63;
    {
      int row = k0 + ((fb >> 1) << 4) + (ln & 15);
      int d0  = ((fb & 1) << 5) + ((ln >> 4) << 3);
      const float* p = K + row * 64 + d0;
      st.ka[i][0] = *(const f32x4*)p;
      st.ka[i][1] = *(const f32x4*)(p + 4);
    }
    {
      int t = fb >> 2, dt = fb & 3;
      int dd = dt * 16 + (ln & 15);
      int kk = k0 + t * 32 + ((ln >> 4) << 2);
      const float* p = V + kk * 64 + dd;
#pragma unroll
      for (int j = 0; j < 4; ++j) { st.vs[i][j] = p[j * 64]; st.vs[i][4 + j] = p[(16 + j) * 64]; }
    }
  }
}

static __device__ __forceinline__ void stage_write(short* kf, short* vf, int tid, const Stage& st) {
#pragma unroll
  for (int i = 0; i < 2; ++i) {
    int s = tid + i * 256;
    s16x8 kr, vr;
#pragma unroll
    for (int e = 0; e < 4; ++e) { kr[e] = f2bf(st.ka[i][0][e]); kr[4 + e] = f2bf(st.ka[i][1][e]); }
#pragma unroll
    for (int e = 0; e < 8; ++e) vr[e] = f2bf(st.vs[i][e]);
    *(s16x8*)(kf + s * 8) = kr;
    *(s16x8*)(vf + s * 8) = vr;
  }
}

extern "C" __global__ void __launch_bounds__(256, 2)
swa_fused_kernel(const float* __restrict__ qg, const float* __restrict__ kg,
                 const float* __restrict__ vg, float* __restrict__ outg,
                 float* __restrict__ ws) {
  __shared__ __align__(16) short KB[2][4096];
  __shared__ __align__(16) short VB[2][4096];

  const int tid = threadIdx.x;
  const int w  = tid >> 6;
  const int l  = tid & 63;
  const int g  = l >> 4;
  const int ql = l & 15;
  const int bx = blockIdx.x;
  const int t  = bx >> 5;     // 0..15 banded tile, 16..23 global chunk
  const int bh = bx & 31;     // bh%8 -> XCD co-location

  const float* Q = qg + (size_t)bh * S_LEN * D_HEAD;
  const float* K = kg + (size_t)bh * S_LEN * D_HEAD;
  const float* V = vg + (size_t)bh * S_LEN * D_HEAD;
  float* O = outg + (size_t)bh * S_LEN * D_HEAD;

  Stage st;

  if (t >= 16) {
    // -------- global-prefix chunk: rows 0..63 over keys [c*512, c*512+512) --------
    const int c = t - 16;
    const int qrow = w * 16 + ql;
    s16x8 qf[2];
#pragma unroll
    for (int h = 0; h < 2; ++h) {
      const float* p = Q + qrow * 64 + h * 32 + g * 8;
      f32x4 a = *(const f32x4*)p, b = *(const f32x4*)(p + 4);
      s16x8 r;
#pragma unroll
      for (int e = 0; e < 4; ++e) { r[e] = f2bf(a[e] * SCALE_L2); r[4 + e] = f2bf(b[e] * SCALE_L2); }
      qf[h] = r;
    }
    f32x4 acc[4] = {{0,0,0,0},{0,0,0,0},{0,0,0,0},{0,0,0,0}};
    float m = MINIT, lsum = 0.f;

    stage_load(K, V, c * 512, tid, st);
    stage_write(KB[0], VB[0], tid, st);
    __syncthreads();
    int cur = 0;
    for (int kb = 0; kb < 8; ++kb) {
      if (kb < 7) stage_load(K, V, c * 512 + (kb + 1) * 64, tid, st);
      const short* kf = KB[cur];
      const short* vf = VB[cur];
      f32x4 cs[4];
#pragma unroll
      for (int kt = 0; kt < 4; ++kt) {
        s16x8 a0 = *(const s16x8*)(kf + ((kt * 2 + 0) * 64 + l) * 8);
        s16x8 a1 = *(const s16x8*)(kf + ((kt * 2 + 1) * 64 + l) * 8);
        f32x4 z = {0,0,0,0};
        z = mfma32(a0, qf[0], z);
        cs[kt] = mfma32(a1, qf[1], z);
      }
      float rm = MASKV;
#pragma unroll
      for (int kt = 0; kt < 4; ++kt)
#pragma unroll
        for (int r = 0; r < 4; ++r) rm = fmaxf(rm, cs[kt][r]);
      rm = fmaxf(rm, __shfl_xor(rm, 16));
      rm = fmaxf(rm, __shfl_xor(rm, 32));
      float mn = fmaxf(m, rm);
      float al = __builtin_amdgcn_exp2f(m - mn);
      float pv[4][4];
      float rs = 0.f;
#pragma unroll
      for (int kt = 0; kt < 4; ++kt)
#pragma unroll
        for (int r = 0; r < 4; ++r) { float e2 = __builtin_amdgcn_exp2f(cs[kt][r] - mn); pv[kt][r] = e2; rs += e2; }
      rs += __shfl_xor(rs, 16);
      rs += __shfl_xor(rs, 32);
      lsum = lsum * al + rs;
      m = mn;
#pragma unroll
      for (int dt = 0; dt < 4; ++dt) acc[dt] *= al;
#pragma unroll
      for (int tt = 0; tt < 2; ++tt) {
        s16x8 pb;
#pragma unroll
        for (int r = 0; r < 4; ++r) { pb[r] = f2bf(pv[2 * tt][r]); pb[4 + r] = f2bf(pv[2 * tt + 1][r]); }
#pragma unroll
        for (int dt = 0; dt < 4; ++dt) {
          s16x8 vfr = *(const s16x8*)(vf + ((tt * 4 + dt) * 64 + l) * 8);
          acc[dt] = mfma32(vfr, pb, acc[dt]);
        }
      }
      if (kb < 7) stage_write(KB[cur ^ 1], VB[cur ^ 1], tid, st);
      __syncthreads();
      cur ^= 1;
    }
    // write unnormalized partial + (m, l) to workspace
    float* wacc = ws + (((size_t)(bh * NCHUNK + c) * 64) + qrow) * 64;
#pragma unroll
    for (int dt = 0; dt < 4; ++dt)
      *(f32x4*)(wacc + dt * 16 + g * 4) = acc[dt];
    if (g == 0) {
      float* wml = ws + ACC_WS_FLOATS + ((size_t)(bh * NCHUNK + c) * 64 + qrow) * 2;
      wml[0] = m; wml[1] = lsum;
    }
    return;
  }

  // ---------------- banded path: 256 queries/block, 4 q-tiles per wave ----------------
  const int tb = t;
  const int qbase = tb * 256 + w * 64;

  s16x8 qf[4][2];
#pragma unroll
  for (int qt = 0; qt < 4; ++qt)
#pragma unroll
    for (int h = 0; h < 2; ++h) {
      const float* p = Q + (qbase + qt * 16 + ql) * 64 + h * 32 + g * 8;
      f32x4 a = *(const f32x4*)p, b = *(const f32x4*)(p + 4);
      s16x8 r;
#pragma unroll
      for (int e = 0; e < 4; ++e) { r[e] = f2bf(a[e] * SCALE_L2); r[4 + e] = f2bf(b[e] * SCALE_L2); }
      qf[qt][h] = r;
    }

  f32x4 acc[4][4];
#pragma unroll
  for (int qt = 0; qt < 4; ++qt)
#pragma unroll
    for (int dt = 0; dt < 4; ++dt) acc[qt][dt] = f32x4{0,0,0,0};
  float mm[4] = {MINIT, MINIT, MINIT, MINIT};
  float ll[4] = {0.f, 0.f, 0.f, 0.f};

  const int kbs = (tb >= 2) ? (4 * tb - 8) : 0;
  const int kbe = 4 * tb + 3;

  stage_load(K, V, kbs * 64, tid, st);
  stage_write(KB[0], VB[0], tid, st);
  __syncthreads();
  int cur = 0;
  for (int kb = kbs; kb <= kbe; ++kb) {
    if (kb < kbe) stage_load(K, V, (kb + 1) * 64, tid, st);
    const short* kf = KB[cur];
    const short* vf = VB[cur];

    f32x4 c[4][4];
#pragma unroll
    for (int kt = 0; kt < 4; ++kt) {
      s16x8 a0 = *(const s16x8*)(kf + ((kt * 2 + 0) * 64 + l) * 8);
      s16x8 a1 = *(const s16x8*)(kf + ((kt * 2 + 1) * 64 + l) * 8);
#pragma unroll
      for (int qt = 0; qt < 4; ++qt) {
        f32x4 z = {0,0,0,0};
        z = mfma32(a0, qf[qt][0], z);
        c[qt][kt] = mfma32(a1, qf[qt][1], z);
      }
    }

    const bool needmask = (kb < 4 * tb - 4) || (kb > 4 * tb - 1);

    s16x8 pbq[4][2];
#pragma unroll
    for (int qt = 0; qt < 4; ++qt) {
      const int qrow = qbase + qt * 16 + ql;
      if (needmask) {
#pragma unroll
        for (int kt = 0; kt < 4; ++kt)
#pragma unroll
          for (int r = 0; r < 4; ++r) {
            int j = kb * 64 + kt * 16 + g * 4 + r;
            bool ok = (j <= qrow) && (j >= qrow - 511);
            c[qt][kt][r] = ok ? c[qt][kt][r] : MASKV;
          }
      }
      float rm = MASKV;
#pragma unroll
      for (int kt = 0; kt < 4; ++kt)
#pragma unroll
        for (int r = 0; r < 4; ++r) rm = fmaxf(rm, c[qt][kt][r]);
      rm = fmaxf(rm, __shfl_xor(rm, 16));
      rm = fmaxf(rm, __shfl_xor(rm, 32));
      float mn = fmaxf(mm[qt], rm);
      float al = __builtin_amdgcn_exp2f(mm[qt] - mn);
      float pv[4][4];
      float rs = 0.f;
#pragma unroll
      for (int kt = 0; kt < 4; ++kt)
#pragma unroll
        for (int r = 0; r < 4; ++r) { float e2 = __builtin_amdgcn_exp2f(c[qt][kt][r] - mn); pv[kt][r] = e2; rs += e2; }
      rs += __shfl_xor(rs, 16);
      rs += __shfl_xor(rs, 32);
      ll[qt] = ll[qt] * al + rs;
      mm[qt] = mn;
#pragma unroll
      for (int dt = 0; dt < 4; ++dt) acc[qt][dt] *= al;
#pragma unroll
      for (int tt = 0; tt < 2; ++tt) {
        s16x8 pb;
#pragma unroll
        for (int r = 0; r < 4; ++r) { pb[r] = f2bf(pv[2 * tt][r]); pb[4 + r] = f2bf(pv[2 * tt + 1][r]); }
        pbq[qt][tt] = pb;
      }
    }

#pragma unroll
    for (int tt = 0; tt < 2; ++tt)
#pragma unroll
      for (int dt = 0; dt < 4; ++dt) {
        s16x8 vfr = *(const s16x8*)(vf + ((tt * 4 + dt) * 64 + l) * 8);
#pragma unroll
        for (int qt = 0; qt < 4; ++qt)
          acc[qt][dt] = mfma32(vfr, pbq[qt][tt], acc[qt][dt]);
      }

    if (kb < kbe) stage_write(KB[cur ^ 1], VB[cur ^ 1], tid, st);
    __syncthreads();
    cur ^= 1;
  }

  // epilogue: rows 0..63 are written by the merge kernel
#pragma unroll
  for (int qt = 0; qt < 4; ++qt) {
    if (qbase + qt * 16 >= 64) {
      const int qrow = qbase + qt * 16 + ql;
      const float inv = 1.0f / ll[qt];
#pragma unroll
      for (int dt = 0; dt < 4; ++dt) {
        f32x4 o = acc[qt][dt] * inv;
        *(f32x4*)(O + (size_t)qrow * 64 + dt * 16 + g * 4) = o;
      }
    }
  }
}

// LSE-merge of the 8 global-prefix partials per bh (rows 0..63).
extern "C" __global__ void __launch_bounds__(256)
swa_merge_kernel(const float* __restrict__ ws, float* __restrict__ outg) {
  const int bh  = blockIdx.x;
  const int tid = threadIdx.x;
  const int row = tid >> 2;          // 0..63
  const int d0  = (tid & 3) * 16;    // 16 floats per thread

  const float* wml = ws + ACC_WS_FLOATS;
  float mc[NCHUNK], lc[NCHUNK];
  float M = MASKV;
#pragma unroll
  for (int c = 0; c < NCHUNK; ++c) {
    const float* p = wml + ((size_t)(bh * NCHUNK + c) * 64 + row) * 2;
    mc[c] = p[0]; lc[c] = p[1];
    M = fmaxf(M, mc[c]);
  }
  float L = 0.f, sc[NCHUNK];
#pragma unroll
  for (int c = 0; c < NCHUNK; ++c) { sc[c] = __builtin_amdgcn_exp2f(mc[c] - M); L += lc[c] * sc[c]; }
  const float inv = 1.0f / L;

  f32x4 o[4] = {{0,0,0,0},{0,0,0,0},{0,0,0,0},{0,0,0,0}};
#pragma unroll
  for (int c = 0; c < NCHUNK; ++c) {
    const float* pa = ws + (((size_t)(bh * NCHUNK + c) * 64) + row) * 64 + d0;
#pragma unroll
    for (int j = 0; j < 4; ++j) {
      f32x4 a = *(const f32x4*)(pa + j * 4);
      o[j] += a * sc[c];
    }
  }
  float* po = outg + ((size_t)bh * S_LEN + row) * 64 + d0;
#pragma unroll
  for (int j = 0; j < 4; ++j) *(f32x4*)(po + j * 4) = o[j] * inv;
}

extern "C" void kernel_launch(void* const* d_in, const int* in_sizes, int n_in,
                              void* d_out, int out_size, void* d_ws, size_t ws_size,
                              hipStream_t stream) {
  (void)in_sizes; (void)n_in; (void)ws_size; (void)out_size;
  const float* q = (const float*)d_in[0];
  const float* k = (const float*)d_in[1];
  const float* v = (const float*)d_in[2];
  float* o = (float*)d_out;
  float* ws = (float*)d_ws;
  // rows 0..15: banded 256-query tiles (longest first); rows 16..23: global chunks.
  dim3 grid(24 * 32), block(256);
  hipLaunchKernelGGL(swa_fused_kernel, grid, block, 0, stream, q, k, v, o, ws);
  hipLaunchKernelGGL(swa_merge_kernel, dim3(32), block, 0, stream, ws, o);
}